// Round 20
// baseline (306.182 us; speedup 1.0000x reference)
//
#include <hip/hip_runtime.h>
#include <hip/hip_fp16.h>
#include <math.h>

#define N_NODES 50000
#define E_EDGES 800000
#define ETOT    850000   // E + N self loops
#define NB_E    3125     // E_EDGES / 256 exactly
#define NB_ET   3321     // ceil(ETOT / 256)
#define NB_X16  6250     // N_NODES*32 / 256
#define NEG     0.2f

typedef _Float16 f16x8 __attribute__((ext_vector_type(8)));
typedef float    f32x4 __attribute__((ext_vector_type(4)));

__device__ __forceinline__ float nt_half(const __half* p) {
  union { unsigned short u; __half h; } c;
  c.u = __builtin_nontemporal_load(reinterpret_cast<const unsigned short*>(p));
  return __half2float(c.h);
}

// ---------------------------------------------------------------- CSR build
__global__ __launch_bounds__(256) void k_init(int* counts) {
  int i = blockIdx.x * 256 + threadIdx.x;
  if (i < N_NODES) counts[i] = 1;          // reserve rank 0 for self loop
}

__global__ __launch_bounds__(256) void k_count(const int* __restrict__ ei, int* counts, int* rank) {
  int e = blockIdx.x * 256 + threadIdx.x;
  if (e >= E_EDGES) return;
  int d = ei[E_EDGES + e];
  rank[e] = atomicAdd(&counts[d], 1);
}

__global__ __launch_bounds__(256) void k_scan1(const int* __restrict__ counts, int* offs, int* bsum) {
  __shared__ int lds[256];
  int t = threadIdx.x;
  int i = blockIdx.x * 256 + t;
  int v = (i < N_NODES) ? counts[i] : 0;
  lds[t] = v;
  __syncthreads();
  for (int s = 1; s < 256; s <<= 1) {
    int add = (t >= s) ? lds[t - s] : 0;
    __syncthreads();
    lds[t] += add;
    __syncthreads();
  }
  if (i < N_NODES) offs[i] = lds[t] - v;   // exclusive within chunk
  if (t == 255) bsum[blockIdx.x] = lds[255];
}

__global__ __launch_bounds__(256) void k_scan2(int* bsum, int nb) {
  __shared__ int lds[256];
  int t = threadIdx.x;
  int v = (t < nb) ? bsum[t] : 0;
  lds[t] = v;
  __syncthreads();
  for (int s = 1; s < 256; s <<= 1) {
    int add = (t >= s) ? lds[t - s] : 0;
    __syncthreads();
    lds[t] += add;
    __syncthreads();
  }
  if (t < nb) bsum[t] = lds[t] - v;        // exclusive chunk bases
}

__global__ __launch_bounds__(256) void k_scan3(int* offs, const int* __restrict__ bsum) {
  int i = blockIdx.x * 256 + threadIdx.x;
  if (i < N_NODES) offs[i] += bsum[i >> 8];
  if (i == 0) offs[N_NODES] = ETOT;
}

__global__ __launch_bounds__(256) void k_fill(const int* __restrict__ ei, const int* __restrict__ rank,
                                              const int* __restrict__ offs, int* srcp, int* eidp) {
  int idx = blockIdx.x * 256 + threadIdx.x;
  if (idx < E_EDGES) {
    int d = ei[E_EDGES + idx];
    int pos = offs[d] + rank[idx];
    srcp[pos] = ei[idx];
    eidp[pos] = idx;
  } else if (idx < ETOT) {
    int n2 = idx - E_EDGES;
    int pos = offs[n2];                    // self loop at rank 0
    srcp[pos] = n2;
    eidp[pos] = E_EDGES + n2;              // marker: self loop
  }
}

// ---------------- fused prep: [0,NB_X16) x->fp16 | [NB_X16,+192) W transpose | last: wea dots
__global__ __launch_bounds__(256) void k_prep(const float* __restrict__ x, __half* __restrict__ X16,
                                              const float* __restrict__ W, __half* __restrict__ Wtf,
                                              const float* __restrict__ W_edge,
                                              const float* __restrict__ att_edge, float* __restrict__ wea) {
  int bid = blockIdx.x, t = threadIdx.x;
  if (bid < NB_X16) {
    int i = bid * 256 + t;                 // one float4 -> 4 halfs
    float4 v = ((const float4*)x)[i];
    __half h[4] = {__float2half(v.x), __float2half(v.y), __float2half(v.z), __float2half(v.w)};
    *(float2*)(X16 + (size_t)i * 4) = *(float2*)h;
  } else if (bid < NB_X16 + 192) {
    // W[l][128k][128n] -> Wtf fp16 [l][col][128], fragment-ordered:
    // p = ks*32 + g*8 + j  maps to  k = ks*32 + 4g + (j&3) + 16*(j>>2)
    int idx = (bid - NB_X16) * 256 + t;
    int l = idx >> 14, rem = idx & 16383, col = rem >> 7, p = rem & 127;
    int ks = p >> 5, q = p & 31, g = q >> 3, j = q & 7;
    int k = ks * 32 + 4 * g + (j & 3) + 16 * (j >> 2);
    Wtf[idx] = __float2half(W[l * 16384 + k * 128 + col]);
  } else {
    if (t >= 192) return;                  // wea[l*64 + d*4 + h]
    int l = t >> 6, rem = t & 63, d = rem >> 2, h = rem & 3;
    const float* wp = W_edge + l * 2048 + d * 128 + h * 32;
    const float* ap = att_edge + l * 128 + h * 32;
    float s = 0.f;
#pragma unroll
    for (int c = 0; c < 32; ++c) s += wp[c] * ap[c];
    wea[t] = s;
  }
}

// ------------------------------------------- edge-feature logits in CSR ORDER (all 3 layers).
// et stored fp16 (logits O(1): quantum ~2e-4, cancels in softmax normalization).
__global__ __launch_bounds__(256) void k_eterm(const int* __restrict__ eidp, const float* __restrict__ ea,
                                               const float* __restrict__ weav,
                                               __half* __restrict__ et16, float* __restrict__ etpart) {
  __shared__ float wl[192];
  __shared__ float red[4][12];
  int t = threadIdx.x;
  if (t < 192) wl[t] = weav[t];
  __syncthreads();
  int pos = blockIdx.x * 256 + t;
  float et[3][4] = {{0.f,0.f,0.f,0.f},{0.f,0.f,0.f,0.f},{0.f,0.f,0.f,0.f}};
  if (pos < ETOT) {
    int eid = eidp[pos];
    if (eid < E_EDGES) {
      float4 Eb[4];
      Eb[0] = *(const float4*)(ea + (long long)eid * 16 + 0);
      Eb[1] = *(const float4*)(ea + (long long)eid * 16 + 4);
      Eb[2] = *(const float4*)(ea + (long long)eid * 16 + 8);
      Eb[3] = *(const float4*)(ea + (long long)eid * 16 + 12);
      const float* ev = (const float*)Eb;
#pragma unroll
      for (int d = 0; d < 16; ++d) {
        float x = ev[d];
#pragma unroll
        for (int l = 0; l < 3; ++l) {
          et[l][0] += x * wl[l * 64 + d * 4 + 0];
          et[l][1] += x * wl[l * 64 + d * 4 + 1];
          et[l][2] += x * wl[l * 64 + d * 4 + 2];
          et[l][3] += x * wl[l * 64 + d * 4 + 3];
        }
      }
#pragma unroll
      for (int l = 0; l < 3; ++l) {
        __half h[4] = {__float2half(et[l][0]), __float2half(et[l][1]),
                       __float2half(et[l][2]), __float2half(et[l][3])};
        *(float2*)&et16[((size_t)l * ETOT + pos) * 4] = *(float2*)h;
      }
    }
  }
#pragma unroll
  for (int l = 0; l < 3; ++l)
#pragma unroll
    for (int h = 0; h < 4; ++h) {
      float v = et[l][h];
      v += __shfl_xor(v, 1);  v += __shfl_xor(v, 2);  v += __shfl_xor(v, 4);
      v += __shfl_xor(v, 8);  v += __shfl_xor(v, 16); v += __shfl_xor(v, 32);
      et[l][h] = v;
    }
  int wv = t >> 6;
  if ((t & 63) == 0) {
#pragma unroll
    for (int l = 0; l < 3; ++l)
#pragma unroll
      for (int h = 0; h < 4; ++h) red[wv][l * 4 + h] = et[l][h];
  }
  __syncthreads();
  if (t < 12) {
    etpart[t * NB_ET + blockIdx.x] = red[0][t] + red[1][t] + red[2][t] + red[3][t];
  }
}

__global__ __launch_bounds__(256) void k_etsum(const float* __restrict__ etpart, float* etsum) {
  __shared__ float lds[256];
  int t = threadIdx.x, v = blockIdx.x;
  float s = 0.f;
  for (int i = t; i < NB_ET; i += 256) s += etpart[v * NB_ET + i];
  lds[t] = s;
  __syncthreads();
  for (int h = 128; h >= 1; h >>= 1) { if (t < h) lds[t] += lds[t + h]; __syncthreads(); }
  if (t == 0) etsum[v] = lds[0] * (1.0f / E_EDGES);
}

__global__ __launch_bounds__(256) void k_selffill(const int* __restrict__ offs, const float* __restrict__ etsum,
                                                  __half* __restrict__ et16) {
  int n = blockIdx.x * 256 + threadIdx.x;
  if (n >= N_NODES) return;
  int pos = offs[n];
#pragma unroll
  for (int l = 0; l < 3; ++l) {
    __half h[4] = {__float2half(etsum[l * 4 + 0]), __float2half(etsum[l * 4 + 1]),
                   __float2half(etsum[l * 4 + 2]), __float2half(etsum[l * 4 + 3])};
    *(float2*)&et16[((size_t)l * ETOT + pos) * 4] = *(float2*)h;
  }
}

// ------------- MFMA GEMM: A16[N,128] = fp16( in16[N,128] @ W ), fused att-dot epilogue.
__global__ __launch_bounds__(256) void k_gemm(const __half* __restrict__ in16, const __half* __restrict__ Wtf_l,
                                              __half* __restrict__ Y16,
                                              const float* __restrict__ att_s, const float* __restrict__ att_d,
                                              float* __restrict__ as_, float* __restrict__ ad_) {
  __shared__ __half wlds[128 * 136];       // 34.8 KB
  int tid = threadIdx.x;
#pragma unroll
  for (int i = 0; i < 8; ++i) {
    int f4 = tid + i * 256;                // 2048 x 16B
    int col = f4 >> 4, chunk = f4 & 15;
    *(float4*)&wlds[col * 136 + chunk * 8] = *(const float4*)(Wtf_l + col * 128 + chunk * 8);
  }
  __syncthreads();

  int w = tid >> 6, l = tid & 63;
  int cidx = l & 15, g = l >> 4;
  int rbase = blockIdx.x * 64 + w * 16;
  int rload = min(rbase + cidx, N_NODES - 1);
  const __half* xbase = in16 + (size_t)rload * 128;

  f32x4 acc[8];
#pragma unroll
  for (int ct = 0; ct < 8; ++ct) acc[ct] = (f32x4){0.f, 0.f, 0.f, 0.f};

#pragma unroll
  for (int ks = 0; ks < 4; ++ks) {
    const __half* xr = xbase + ks * 32 + 4 * g;
    union { uint2 u2[2]; f16x8 v; } au;
    au.u2[0] = *(const uint2*)(xr);        // k = ks*32 + 4g + 0..3
    au.u2[1] = *(const uint2*)(xr + 16);   // k = ks*32 + 16 + 4g + 0..3
    f16x8 a = au.v;
#pragma unroll
    for (int ct = 0; ct < 8; ++ct) {
      f16x8 b = *(const f16x8*)&wlds[(ct * 16 + cidx) * 136 + ks * 32 + g * 8];
      acc[ct] = __builtin_amdgcn_mfma_f32_16x16x32_f16(a, b, acc[ct], 0, 0, 0);
    }
  }

#pragma unroll
  for (int ct = 0; ct < 8; ++ct) {
    int col = ct * 16 + cidx;
#pragma unroll
    for (int reg = 0; reg < 4; ++reg) {
      int r2 = rbase + 4 * g + reg;
      if (r2 < N_NODES) Y16[(size_t)r2 * 128 + col] = __float2half(acc[ct][reg]);
    }
  }
#pragma unroll
  for (int hd = 0; hd < 4; ++hd) {
    float a1 = att_s[hd * 32 + cidx],      a2 = att_s[hd * 32 + 16 + cidx];
    float d1 = att_d[hd * 32 + cidx],      d2 = att_d[hd * 32 + 16 + cidx];
    float ts[4], td[4];
#pragma unroll
    for (int reg = 0; reg < 4; ++reg) {
      ts[reg] = acc[2 * hd][reg] * a1 + acc[2 * hd + 1][reg] * a2;
      td[reg] = acc[2 * hd][reg] * d1 + acc[2 * hd + 1][reg] * d2;
    }
#pragma unroll
    for (int reg = 0; reg < 4; ++reg) {
      ts[reg] += __shfl_xor(ts[reg], 1); ts[reg] += __shfl_xor(ts[reg], 2);
      ts[reg] += __shfl_xor(ts[reg], 4); ts[reg] += __shfl_xor(ts[reg], 8);
      td[reg] += __shfl_xor(td[reg], 1); td[reg] += __shfl_xor(td[reg], 2);
      td[reg] += __shfl_xor(td[reg], 4); td[reg] += __shfl_xor(td[reg], 8);
    }
    if (cidx == 0) {
#pragma unroll
      for (int reg = 0; reg < 4; ++reg) {
        int r2 = rbase + 4 * g + reg;
        if (r2 < N_NODES) { as_[r2 * 4 + hd] = ts[reg]; ad_[r2 * 4 + hd] = td[reg]; }
      }
    }
  }
}

// -------------------------------- aggregation, SINGLE-PASS fused softmax, 32 lanes/node.
// srcp/et16 are read-once streams -> nontemporal loads (keep L2 for the H16 gather).
__global__ __launch_bounds__(256) void k_agg(const __half* __restrict__ H16,
                                             const __half* __restrict__ et_l,
                                             const float* __restrict__ as_, const float* __restrict__ ad_,
                                             const int* __restrict__ offs, const int* __restrict__ srcp,
                                             const float* __restrict__ bias,
                                             __half* __restrict__ outH, float* __restrict__ outF, int last) {
  int tid = threadIdx.x;
  int q = tid & 31;
  int n2 = blockIdx.x * 8 + (tid >> 5);
  if (n2 >= N_NODES) return;
  int off0 = offs[n2], off1 = offs[n2 + 1];
  int hh = q >> 3;
  float adh = ad_[n2 * 4 + hh];

  float csum = 0.f;
  float4 acc = make_float4(0.f, 0.f, 0.f, 0.f);
  const long long qq = 4 * q;
  int j = off0;
  for (; j + 3 < off1; j += 4) {
    int s0 = __builtin_nontemporal_load(srcp + j);
    int s1 = __builtin_nontemporal_load(srcp + j + 1);
    int s2 = __builtin_nontemporal_load(srcp + j + 2);
    int s3 = __builtin_nontemporal_load(srcp + j + 3);
    float v0 = nt_half(et_l + (size_t)j * 4 + hh)       + as_[s0 * 4 + hh] + adh;
    float v1 = nt_half(et_l + (size_t)(j + 1) * 4 + hh) + as_[s1 * 4 + hh] + adh;
    float v2 = nt_half(et_l + (size_t)(j + 2) * 4 + hh) + as_[s2 * 4 + hh] + adh;
    float v3 = nt_half(et_l + (size_t)(j + 3) * 4 + hh) + as_[s3 * 4 + hh] + adh;
    v0 = v0 > 0.f ? v0 : NEG * v0;  v1 = v1 > 0.f ? v1 : NEG * v1;
    v2 = v2 > 0.f ? v2 : NEG * v2;  v3 = v3 > 0.f ? v3 : NEG * v3;
    float c0 = __expf(v0), c1 = __expf(v1), c2 = __expf(v2), c3 = __expf(v3);
    float2 r0 = *(const float2*)(H16 + (long long)s0 * 128 + qq);
    float2 r1 = *(const float2*)(H16 + (long long)s1 * 128 + qq);
    float2 r2 = *(const float2*)(H16 + (long long)s2 * 128 + qq);
    float2 r3 = *(const float2*)(H16 + (long long)s3 * 128 + qq);
    csum += c0 + c1 + c2 + c3;
    const __half2* p0 = (const __half2*)&r0; const __half2* p1 = (const __half2*)&r1;
    const __half2* p2 = (const __half2*)&r2; const __half2* p3 = (const __half2*)&r3;
    float2 a0 = __half22float2(p0[0]), b0 = __half22float2(p0[1]);
    float2 a1 = __half22float2(p1[0]), b1 = __half22float2(p1[1]);
    float2 a2 = __half22float2(p2[0]), b2 = __half22float2(p2[1]);
    float2 a3 = __half22float2(p3[0]), b3 = __half22float2(p3[1]);
    acc.x += c0 * a0.x + c1 * a1.x + c2 * a2.x + c3 * a3.x;
    acc.y += c0 * a0.y + c1 * a1.y + c2 * a2.y + c3 * a3.y;
    acc.z += c0 * b0.x + c1 * b1.x + c2 * b2.x + c3 * b3.x;
    acc.w += c0 * b0.y + c1 * b1.y + c2 * b2.y + c3 * b3.y;
  }
  for (; j < off1; ++j) {
    int s0 = __builtin_nontemporal_load(srcp + j);
    float v0 = nt_half(et_l + (size_t)j * 4 + hh) + as_[s0 * 4 + hh] + adh;
    v0 = v0 > 0.f ? v0 : NEG * v0;
    float c0 = __expf(v0);
    csum += c0;
    float2 r0 = *(const float2*)(H16 + (long long)s0 * 128 + qq);
    const __half2* p0 = (const __half2*)&r0;
    float2 a0 = __half22float2(p0[0]), b0 = __half22float2(p0[1]);
    acc.x += c0 * a0.x; acc.y += c0 * a0.y; acc.z += c0 * b0.x; acc.w += c0 * b0.y;
  }
  float inv = 1.f / (csum + 1e-16f);
  acc.x *= inv; acc.y *= inv; acc.z *= inv; acc.w *= inv;

  if (!last) {
    const float4 bv = *(const float4*)(bias + 4 * q);
    __half h[4] = {__float2half(acc.x + bv.x), __float2half(acc.y + bv.y),
                   __float2half(acc.z + bv.z), __float2half(acc.w + bv.w)};
    *(float2*)(outH + (long long)n2 * 128 + 4 * q) = *(float2*)h;
  } else {
    acc.x += __shfl_xor(acc.x, 8); acc.x += __shfl_xor(acc.x, 16);
    acc.y += __shfl_xor(acc.y, 8); acc.y += __shfl_xor(acc.y, 16);
    acc.z += __shfl_xor(acc.z, 8); acc.z += __shfl_xor(acc.z, 16);
    acc.w += __shfl_xor(acc.w, 8); acc.w += __shfl_xor(acc.w, 16);
    if (q < 8) {
      const float4 bv = *(const float4*)(bias + 4 * q);
      *(float4*)(outF + (long long)n2 * 32 + 4 * q) =
          make_float4(0.25f * acc.x + bv.x, 0.25f * acc.y + bv.y,
                      0.25f * acc.z + bv.z, 0.25f * acc.w + bv.w);
    }
  }
}

// ---------------------------------------------------------------- launch
extern "C" void kernel_launch(void* const* d_in, const int* in_sizes, int n_in,
                              void* d_out, int out_size, void* d_ws, size_t ws_size,
                              hipStream_t stream) {
  const float* x         = (const float*)d_in[0];
  const float* edge_attr = (const float*)d_in[1];
  const int*   ei        = (const int*)d_in[2];
  const float* W         = (const float*)d_in[3];
  const float* att_src   = (const float*)d_in[4];
  const float* att_dst   = (const float*)d_in[5];
  const float* W_edge    = (const float*)d_in[6];
  const float* att_edge  = (const float*)d_in[7];
  const float* bias_cat  = (const float*)d_in[8];
  const float* bias_last = (const float*)d_in[9];

  char* w = (char*)d_ws;
  auto alloc = [&](size_t bytes) { char* p = w; w += (bytes + 255) & ~(size_t)255; return p; };
  __half* A16   = (__half*)alloc(sizeof(__half) * (size_t)N_NODES * 128);
  __half* B16   = (__half*)alloc(sizeof(__half) * (size_t)N_NODES * 128);
  __half* X16   = (__half*)alloc(sizeof(__half) * (size_t)N_NODES * 128);
  __half* Wtf   = (__half*)alloc(sizeof(__half) * 3 * 128 * 128);
  __half* et16  = (__half*)alloc(sizeof(__half) * (size_t)3 * ETOT * 4);  // 20.4 MB
  float* as_    = (float*)alloc(sizeof(float) * N_NODES * 4);
  float* ad_    = (float*)alloc(sizeof(float) * N_NODES * 4);
  float* weav   = (float*)alloc(sizeof(float) * 192);
  float* etpart = (float*)alloc(sizeof(float) * 12 * NB_ET);
  float* etsum  = (float*)alloc(sizeof(float) * 16);
  int* counts   = (int*)alloc(sizeof(int) * N_NODES);
  int* offs     = (int*)alloc(sizeof(int) * (N_NODES + 1));
  int* srcp     = (int*)alloc(sizeof(int) * ETOT);
  int* eidp     = (int*)alloc(sizeof(int) * ETOT);
  int* rank     = (int*)alloc(sizeof(int) * E_EDGES);
  int* bsum     = (int*)alloc(sizeof(int) * 256);

  const int nbN = (N_NODES + 255) / 256;   // 196

  hipLaunchKernelGGL(k_init,  dim3(nbN), dim3(256), 0, stream, counts);
  hipLaunchKernelGGL(k_count, dim3(NB_E), dim3(256), 0, stream, ei, counts, rank);
  hipLaunchKernelGGL(k_scan1, dim3(nbN), dim3(256), 0, stream, counts, offs, bsum);
  hipLaunchKernelGGL(k_scan2, dim3(1),   dim3(256), 0, stream, bsum, nbN);
  hipLaunchKernelGGL(k_scan3, dim3(nbN), dim3(256), 0, stream, offs, bsum);
  hipLaunchKernelGGL(k_fill,  dim3((ETOT + 255) / 256), dim3(256), 0, stream, ei, rank, offs, srcp, eidp);
  hipLaunchKernelGGL(k_prep,  dim3(NB_X16 + 192 + 1), dim3(256), 0, stream,
                     x, X16, W, Wtf, W_edge, att_edge, weav);
  hipLaunchKernelGGL(k_eterm, dim3(NB_ET), dim3(256), 0, stream, eidp, edge_attr, weav, et16, etpart);
  hipLaunchKernelGGL(k_etsum, dim3(12), dim3(256), 0, stream, etpart, etsum);
  hipLaunchKernelGGL(k_selffill, dim3(nbN), dim3(256), 0, stream, offs, etsum, et16);

  const __half* hin = X16;
  for (int lyr = 0; lyr < 3; ++lyr) {
    int last = (lyr == 2);
    hipLaunchKernelGGL(k_gemm, dim3((N_NODES + 63) / 64), dim3(256), 0, stream,
                       hin, Wtf + lyr * 16384, A16,
                       att_src + lyr * 128, att_dst + lyr * 128, as_, ad_);
    hipLaunchKernelGGL(k_agg, dim3((N_NODES + 7) / 8), dim3(256), 0, stream,
                       A16, et16 + (size_t)lyr * ETOT * 4, as_, ad_, offs, srcp,
                       last ? bias_last : (bias_cat + lyr * 128),
                       B16, (float*)d_out, last);
    hin = B16;
  }
}

// Round 21
// 280.778 us; speedup vs baseline: 1.0905x; 1.0905x over previous
//
#include <hip/hip_runtime.h>
#include <hip/hip_fp16.h>
#include <math.h>

#define N_NODES 50000
#define E_EDGES 800000
#define ETOT    850000   // E + N self loops
#define NB_E    3125     // E_EDGES / 256 exactly
#define NB_ET   3321     // ceil(ETOT / 256)
#define NB_X16  6250     // N_NODES*32 / 256
#define NEG     0.2f

typedef _Float16 f16x8 __attribute__((ext_vector_type(8)));
typedef float    f32x4 __attribute__((ext_vector_type(4)));

// ---------------------------------------------------------------- CSR build
__global__ __launch_bounds__(256) void k_init(int* counts) {
  int i = blockIdx.x * 256 + threadIdx.x;
  if (i < N_NODES) counts[i] = 1;          // reserve rank 0 for self loop
}

__global__ __launch_bounds__(256) void k_count(const int* __restrict__ ei, int* counts, int* rank) {
  int e = blockIdx.x * 256 + threadIdx.x;
  if (e >= E_EDGES) return;
  int d = ei[E_EDGES + e];
  rank[e] = atomicAdd(&counts[d], 1);
}

__global__ __launch_bounds__(256) void k_scan1(const int* __restrict__ counts, int* offs, int* bsum) {
  __shared__ int lds[256];
  int t = threadIdx.x;
  int i = blockIdx.x * 256 + t;
  int v = (i < N_NODES) ? counts[i] : 0;
  lds[t] = v;
  __syncthreads();
  for (int s = 1; s < 256; s <<= 1) {
    int add = (t >= s) ? lds[t - s] : 0;
    __syncthreads();
    lds[t] += add;
    __syncthreads();
  }
  if (i < N_NODES) offs[i] = lds[t] - v;   // exclusive within chunk
  if (t == 255) bsum[blockIdx.x] = lds[255];
}

__global__ __launch_bounds__(256) void k_scan2(int* bsum, int nb) {
  __shared__ int lds[256];
  int t = threadIdx.x;
  int v = (t < nb) ? bsum[t] : 0;
  lds[t] = v;
  __syncthreads();
  for (int s = 1; s < 256; s <<= 1) {
    int add = (t >= s) ? lds[t - s] : 0;
    __syncthreads();
    lds[t] += add;
    __syncthreads();
  }
  if (t < nb) bsum[t] = lds[t] - v;        // exclusive chunk bases
}

__global__ __launch_bounds__(256) void k_scan3(int* offs, const int* __restrict__ bsum) {
  int i = blockIdx.x * 256 + threadIdx.x;
  if (i < N_NODES) offs[i] += bsum[i >> 8];
  if (i == 0) offs[N_NODES] = ETOT;
}

__global__ __launch_bounds__(256) void k_fill(const int* __restrict__ ei, const int* __restrict__ rank,
                                              const int* __restrict__ offs, int* srcp, int* eidp) {
  int idx = blockIdx.x * 256 + threadIdx.x;
  if (idx < E_EDGES) {
    int d = ei[E_EDGES + idx];
    int pos = offs[d] + rank[idx];
    srcp[pos] = ei[idx];
    eidp[pos] = idx;
  } else if (idx < ETOT) {
    int n2 = idx - E_EDGES;
    int pos = offs[n2];                    // self loop at rank 0
    srcp[pos] = n2;
    eidp[pos] = E_EDGES + n2;              // marker: self loop
  }
}

// ---------------- fused prep: [0,NB_X16) x->fp16 | [NB_X16,+192) W transpose | last: wea dots
__global__ __launch_bounds__(256) void k_prep(const float* __restrict__ x, __half* __restrict__ X16,
                                              const float* __restrict__ W, __half* __restrict__ Wtf,
                                              const float* __restrict__ W_edge,
                                              const float* __restrict__ att_edge, float* __restrict__ wea) {
  int bid = blockIdx.x, t = threadIdx.x;
  if (bid < NB_X16) {
    int i = bid * 256 + t;                 // one float4 -> 4 halfs
    float4 v = ((const float4*)x)[i];
    __half h[4] = {__float2half(v.x), __float2half(v.y), __float2half(v.z), __float2half(v.w)};
    *(float2*)(X16 + (size_t)i * 4) = *(float2*)h;
  } else if (bid < NB_X16 + 192) {
    // W[l][128k][128n] -> Wtf fp16 [l][col][128], fragment-ordered:
    // p = ks*32 + g*8 + j  maps to  k = ks*32 + 4g + (j&3) + 16*(j>>2)
    int idx = (bid - NB_X16) * 256 + t;
    int l = idx >> 14, rem = idx & 16383, col = rem >> 7, p = rem & 127;
    int ks = p >> 5, q = p & 31, g = q >> 3, j = q & 7;
    int k = ks * 32 + 4 * g + (j & 3) + 16 * (j >> 2);
    Wtf[idx] = __float2half(W[l * 16384 + k * 128 + col]);
  } else {
    if (t >= 192) return;                  // wea[l*64 + d*4 + h]
    int l = t >> 6, rem = t & 63, d = rem >> 2, h = rem & 3;
    const float* wp = W_edge + l * 2048 + d * 128 + h * 32;
    const float* ap = att_edge + l * 128 + h * 32;
    float s = 0.f;
#pragma unroll
    for (int c = 0; c < 32; ++c) s += wp[c] * ap[c];
    wea[t] = s;
  }
}

// ------------------------------------------- edge-feature logits in CSR ORDER (all 3 layers).
// et stored fp16 (logits O(1): quantum ~2e-4, cancels in softmax normalization).
__global__ __launch_bounds__(256) void k_eterm(const int* __restrict__ eidp, const float* __restrict__ ea,
                                               const float* __restrict__ weav,
                                               __half* __restrict__ et16, float* __restrict__ etpart) {
  __shared__ float wl[192];
  __shared__ float red[4][12];
  int t = threadIdx.x;
  if (t < 192) wl[t] = weav[t];
  __syncthreads();
  int pos = blockIdx.x * 256 + t;
  float et[3][4] = {{0.f,0.f,0.f,0.f},{0.f,0.f,0.f,0.f},{0.f,0.f,0.f,0.f}};
  if (pos < ETOT) {
    int eid = eidp[pos];
    if (eid < E_EDGES) {
      float4 Eb[4];
      Eb[0] = *(const float4*)(ea + (long long)eid * 16 + 0);
      Eb[1] = *(const float4*)(ea + (long long)eid * 16 + 4);
      Eb[2] = *(const float4*)(ea + (long long)eid * 16 + 8);
      Eb[3] = *(const float4*)(ea + (long long)eid * 16 + 12);
      const float* ev = (const float*)Eb;
#pragma unroll
      for (int d = 0; d < 16; ++d) {
        float x = ev[d];
#pragma unroll
        for (int l = 0; l < 3; ++l) {
          et[l][0] += x * wl[l * 64 + d * 4 + 0];
          et[l][1] += x * wl[l * 64 + d * 4 + 1];
          et[l][2] += x * wl[l * 64 + d * 4 + 2];
          et[l][3] += x * wl[l * 64 + d * 4 + 3];
        }
      }
#pragma unroll
      for (int l = 0; l < 3; ++l) {
        __half h[4] = {__float2half(et[l][0]), __float2half(et[l][1]),
                       __float2half(et[l][2]), __float2half(et[l][3])};
        *(float2*)&et16[((size_t)l * ETOT + pos) * 4] = *(float2*)h;
      }
    }
  }
#pragma unroll
  for (int l = 0; l < 3; ++l)
#pragma unroll
    for (int h = 0; h < 4; ++h) {
      float v = et[l][h];
      v += __shfl_xor(v, 1);  v += __shfl_xor(v, 2);  v += __shfl_xor(v, 4);
      v += __shfl_xor(v, 8);  v += __shfl_xor(v, 16); v += __shfl_xor(v, 32);
      et[l][h] = v;
    }
  int wv = t >> 6;
  if ((t & 63) == 0) {
#pragma unroll
    for (int l = 0; l < 3; ++l)
#pragma unroll
      for (int h = 0; h < 4; ++h) red[wv][l * 4 + h] = et[l][h];
  }
  __syncthreads();
  if (t < 12) {
    etpart[t * NB_ET + blockIdx.x] = red[0][t] + red[1][t] + red[2][t] + red[3][t];
  }
}

__global__ __launch_bounds__(256) void k_etsum(const float* __restrict__ etpart, float* etsum) {
  __shared__ float lds[256];
  int t = threadIdx.x, v = blockIdx.x;
  float s = 0.f;
  for (int i = t; i < NB_ET; i += 256) s += etpart[v * NB_ET + i];
  lds[t] = s;
  __syncthreads();
  for (int h = 128; h >= 1; h >>= 1) { if (t < h) lds[t] += lds[t + h]; __syncthreads(); }
  if (t == 0) etsum[v] = lds[0] * (1.0f / E_EDGES);
}

__global__ __launch_bounds__(256) void k_selffill(const int* __restrict__ offs, const float* __restrict__ etsum,
                                                  __half* __restrict__ et16) {
  int n = blockIdx.x * 256 + threadIdx.x;
  if (n >= N_NODES) return;
  int pos = offs[n];
#pragma unroll
  for (int l = 0; l < 3; ++l) {
    __half h[4] = {__float2half(etsum[l * 4 + 0]), __float2half(etsum[l * 4 + 1]),
                   __float2half(etsum[l * 4 + 2]), __float2half(etsum[l * 4 + 3])};
    *(float2*)&et16[((size_t)l * ETOT + pos) * 4] = *(float2*)h;
  }
}

// ------------- MFMA GEMM: A16[N,128] = fp16( in16[N,128] @ W ), fused att-dot epilogue.
__global__ __launch_bounds__(256) void k_gemm(const __half* __restrict__ in16, const __half* __restrict__ Wtf_l,
                                              __half* __restrict__ Y16,
                                              const float* __restrict__ att_s, const float* __restrict__ att_d,
                                              float* __restrict__ as_, float* __restrict__ ad_) {
  __shared__ __half wlds[128 * 136];       // 34.8 KB
  int tid = threadIdx.x;
#pragma unroll
  for (int i = 0; i < 8; ++i) {
    int f4 = tid + i * 256;                // 2048 x 16B
    int col = f4 >> 4, chunk = f4 & 15;
    *(float4*)&wlds[col * 136 + chunk * 8] = *(const float4*)(Wtf_l + col * 128 + chunk * 8);
  }
  __syncthreads();

  int w = tid >> 6, l = tid & 63;
  int cidx = l & 15, g = l >> 4;
  int rbase = blockIdx.x * 64 + w * 16;
  int rload = min(rbase + cidx, N_NODES - 1);
  const __half* xbase = in16 + (size_t)rload * 128;

  f32x4 acc[8];
#pragma unroll
  for (int ct = 0; ct < 8; ++ct) acc[ct] = (f32x4){0.f, 0.f, 0.f, 0.f};

#pragma unroll
  for (int ks = 0; ks < 4; ++ks) {
    const __half* xr = xbase + ks * 32 + 4 * g;
    union { uint2 u2[2]; f16x8 v; } au;
    au.u2[0] = *(const uint2*)(xr);        // k = ks*32 + 4g + 0..3
    au.u2[1] = *(const uint2*)(xr + 16);   // k = ks*32 + 16 + 4g + 0..3
    f16x8 a = au.v;
#pragma unroll
    for (int ct = 0; ct < 8; ++ct) {
      f16x8 b = *(const f16x8*)&wlds[(ct * 16 + cidx) * 136 + ks * 32 + g * 8];
      acc[ct] = __builtin_amdgcn_mfma_f32_16x16x32_f16(a, b, acc[ct], 0, 0, 0);
    }
  }

#pragma unroll
  for (int ct = 0; ct < 8; ++ct) {
    int col = ct * 16 + cidx;
#pragma unroll
    for (int reg = 0; reg < 4; ++reg) {
      int r2 = rbase + 4 * g + reg;
      if (r2 < N_NODES) Y16[(size_t)r2 * 128 + col] = __float2half(acc[ct][reg]);
    }
  }
#pragma unroll
  for (int hd = 0; hd < 4; ++hd) {
    float a1 = att_s[hd * 32 + cidx],      a2 = att_s[hd * 32 + 16 + cidx];
    float d1 = att_d[hd * 32 + cidx],      d2 = att_d[hd * 32 + 16 + cidx];
    float ts[4], td[4];
#pragma unroll
    for (int reg = 0; reg < 4; ++reg) {
      ts[reg] = acc[2 * hd][reg] * a1 + acc[2 * hd + 1][reg] * a2;
      td[reg] = acc[2 * hd][reg] * d1 + acc[2 * hd + 1][reg] * d2;
    }
#pragma unroll
    for (int reg = 0; reg < 4; ++reg) {
      ts[reg] += __shfl_xor(ts[reg], 1); ts[reg] += __shfl_xor(ts[reg], 2);
      ts[reg] += __shfl_xor(ts[reg], 4); ts[reg] += __shfl_xor(ts[reg], 8);
      td[reg] += __shfl_xor(td[reg], 1); td[reg] += __shfl_xor(td[reg], 2);
      td[reg] += __shfl_xor(td[reg], 4); td[reg] += __shfl_xor(td[reg], 8);
    }
    if (cidx == 0) {
#pragma unroll
      for (int reg = 0; reg < 4; ++reg) {
        int r2 = rbase + 4 * g + reg;
        if (r2 < N_NODES) { as_[r2 * 4 + hd] = ts[reg]; ad_[r2 * 4 + hd] = td[reg]; }
      }
    }
  }
}

// -------------------------------- aggregation, SINGLE-PASS fused softmax, 32 lanes/node
// (round-18 proven version, plain loads — NT loads regressed: FETCH 100->117 MB).
__global__ __launch_bounds__(256) void k_agg(const __half* __restrict__ H16,
                                             const __half* __restrict__ et_l,
                                             const float* __restrict__ as_, const float* __restrict__ ad_,
                                             const int* __restrict__ offs, const int* __restrict__ srcp,
                                             const float* __restrict__ bias,
                                             __half* __restrict__ outH, float* __restrict__ outF, int last) {
  int tid = threadIdx.x;
  int q = tid & 31;
  int n2 = blockIdx.x * 8 + (tid >> 5);
  if (n2 >= N_NODES) return;
  int off0 = offs[n2], off1 = offs[n2 + 1];
  int hh = q >> 3;
  float adh = ad_[n2 * 4 + hh];

  float csum = 0.f;
  float4 acc = make_float4(0.f, 0.f, 0.f, 0.f);
  const long long qq = 4 * q;
  int j = off0;
  for (; j + 3 < off1; j += 4) {
    int s0 = srcp[j], s1 = srcp[j + 1], s2 = srcp[j + 2], s3 = srcp[j + 3];
    float v0 = __half2float(et_l[(size_t)j * 4 + hh])       + as_[s0 * 4 + hh] + adh;
    float v1 = __half2float(et_l[(size_t)(j + 1) * 4 + hh]) + as_[s1 * 4 + hh] + adh;
    float v2 = __half2float(et_l[(size_t)(j + 2) * 4 + hh]) + as_[s2 * 4 + hh] + adh;
    float v3 = __half2float(et_l[(size_t)(j + 3) * 4 + hh]) + as_[s3 * 4 + hh] + adh;
    v0 = v0 > 0.f ? v0 : NEG * v0;  v1 = v1 > 0.f ? v1 : NEG * v1;
    v2 = v2 > 0.f ? v2 : NEG * v2;  v3 = v3 > 0.f ? v3 : NEG * v3;
    float c0 = __expf(v0), c1 = __expf(v1), c2 = __expf(v2), c3 = __expf(v3);
    float2 r0 = *(const float2*)(H16 + (long long)s0 * 128 + qq);
    float2 r1 = *(const float2*)(H16 + (long long)s1 * 128 + qq);
    float2 r2 = *(const float2*)(H16 + (long long)s2 * 128 + qq);
    float2 r3 = *(const float2*)(H16 + (long long)s3 * 128 + qq);
    csum += c0 + c1 + c2 + c3;
    const __half2* p0 = (const __half2*)&r0; const __half2* p1 = (const __half2*)&r1;
    const __half2* p2 = (const __half2*)&r2; const __half2* p3 = (const __half2*)&r3;
    float2 a0 = __half22float2(p0[0]), b0 = __half22float2(p0[1]);
    float2 a1 = __half22float2(p1[0]), b1 = __half22float2(p1[1]);
    float2 a2 = __half22float2(p2[0]), b2 = __half22float2(p2[1]);
    float2 a3 = __half22float2(p3[0]), b3 = __half22float2(p3[1]);
    acc.x += c0 * a0.x + c1 * a1.x + c2 * a2.x + c3 * a3.x;
    acc.y += c0 * a0.y + c1 * a1.y + c2 * a2.y + c3 * a3.y;
    acc.z += c0 * b0.x + c1 * b1.x + c2 * b2.x + c3 * b3.x;
    acc.w += c0 * b0.y + c1 * b1.y + c2 * b2.y + c3 * b3.y;
  }
  for (; j < off1; ++j) {
    int s0 = srcp[j];
    float v0 = __half2float(et_l[(size_t)j * 4 + hh]) + as_[s0 * 4 + hh] + adh;
    v0 = v0 > 0.f ? v0 : NEG * v0;
    float c0 = __expf(v0);
    csum += c0;
    float2 r0 = *(const float2*)(H16 + (long long)s0 * 128 + qq);
    const __half2* p0 = (const __half2*)&r0;
    float2 a0 = __half22float2(p0[0]), b0 = __half22float2(p0[1]);
    acc.x += c0 * a0.x; acc.y += c0 * a0.y; acc.z += c0 * b0.x; acc.w += c0 * b0.y;
  }
  float inv = 1.f / (csum + 1e-16f);
  acc.x *= inv; acc.y *= inv; acc.z *= inv; acc.w *= inv;

  if (!last) {
    const float4 bv = *(const float4*)(bias + 4 * q);
    __half h[4] = {__float2half(acc.x + bv.x), __float2half(acc.y + bv.y),
                   __float2half(acc.z + bv.z), __float2half(acc.w + bv.w)};
    *(float2*)(outH + (long long)n2 * 128 + 4 * q) = *(float2*)h;
  } else {
    acc.x += __shfl_xor(acc.x, 8); acc.x += __shfl_xor(acc.x, 16);
    acc.y += __shfl_xor(acc.y, 8); acc.y += __shfl_xor(acc.y, 16);
    acc.z += __shfl_xor(acc.z, 8); acc.z += __shfl_xor(acc.z, 16);
    acc.w += __shfl_xor(acc.w, 8); acc.w += __shfl_xor(acc.w, 16);
    if (q < 8) {
      const float4 bv = *(const float4*)(bias + 4 * q);
      *(float4*)(outF + (long long)n2 * 32 + 4 * q) =
          make_float4(0.25f * acc.x + bv.x, 0.25f * acc.y + bv.y,
                      0.25f * acc.z + bv.z, 0.25f * acc.w + bv.w);
    }
  }
}

// ---------------------------------------------------------------- launch
extern "C" void kernel_launch(void* const* d_in, const int* in_sizes, int n_in,
                              void* d_out, int out_size, void* d_ws, size_t ws_size,
                              hipStream_t stream) {
  const float* x         = (const float*)d_in[0];
  const float* edge_attr = (const float*)d_in[1];
  const int*   ei        = (const int*)d_in[2];
  const float* W         = (const float*)d_in[3];
  const float* att_src   = (const float*)d_in[4];
  const float* att_dst   = (const float*)d_in[5];
  const float* W_edge    = (const float*)d_in[6];
  const float* att_edge  = (const float*)d_in[7];
  const float* bias_cat  = (const float*)d_in[8];
  const float* bias_last = (const float*)d_in[9];

  char* w = (char*)d_ws;
  auto alloc = [&](size_t bytes) { char* p = w; w += (bytes + 255) & ~(size_t)255; return p; };
  __half* A16   = (__half*)alloc(sizeof(__half) * (size_t)N_NODES * 128);
  __half* B16   = (__half*)alloc(sizeof(__half) * (size_t)N_NODES * 128);
  __half* X16   = (__half*)alloc(sizeof(__half) * (size_t)N_NODES * 128);
  __half* Wtf   = (__half*)alloc(sizeof(__half) * 3 * 128 * 128);
  __half* et16  = (__half*)alloc(sizeof(__half) * (size_t)3 * ETOT * 4);  // 20.4 MB
  float* as_    = (float*)alloc(sizeof(float) * N_NODES * 4);
  float* ad_    = (float*)alloc(sizeof(float) * N_NODES * 4);
  float* weav   = (float*)alloc(sizeof(float) * 192);
  float* etpart = (float*)alloc(sizeof(float) * 12 * NB_ET);
  float* etsum  = (float*)alloc(sizeof(float) * 16);
  int* counts   = (int*)alloc(sizeof(int) * N_NODES);
  int* offs     = (int*)alloc(sizeof(int) * (N_NODES + 1));
  int* srcp     = (int*)alloc(sizeof(int) * ETOT);
  int* eidp     = (int*)alloc(sizeof(int) * ETOT);
  int* rank     = (int*)alloc(sizeof(int) * E_EDGES);
  int* bsum     = (int*)alloc(sizeof(int) * 256);

  const int nbN = (N_NODES + 255) / 256;   // 196

  hipLaunchKernelGGL(k_init,  dim3(nbN), dim3(256), 0, stream, counts);
  hipLaunchKernelGGL(k_count, dim3(NB_E), dim3(256), 0, stream, ei, counts, rank);
  hipLaunchKernelGGL(k_scan1, dim3(nbN), dim3(256), 0, stream, counts, offs, bsum);
  hipLaunchKernelGGL(k_scan2, dim3(1),   dim3(256), 0, stream, bsum, nbN);
  hipLaunchKernelGGL(k_scan3, dim3(nbN), dim3(256), 0, stream, offs, bsum);
  hipLaunchKernelGGL(k_fill,  dim3((ETOT + 255) / 256), dim3(256), 0, stream, ei, rank, offs, srcp, eidp);
  hipLaunchKernelGGL(k_prep,  dim3(NB_X16 + 192 + 1), dim3(256), 0, stream,
                     x, X16, W, Wtf, W_edge, att_edge, weav);
  hipLaunchKernelGGL(k_eterm, dim3(NB_ET), dim3(256), 0, stream, eidp, edge_attr, weav, et16, etpart);
  hipLaunchKernelGGL(k_etsum, dim3(12), dim3(256), 0, stream, etpart, etsum);
  hipLaunchKernelGGL(k_selffill, dim3(nbN), dim3(256), 0, stream, offs, etsum, et16);

  const __half* hin = X16;
  for (int lyr = 0; lyr < 3; ++lyr) {
    int last = (lyr == 2);
    hipLaunchKernelGGL(k_gemm, dim3((N_NODES + 63) / 64), dim3(256), 0, stream,
                       hin, Wtf + lyr * 16384, A16,
                       att_src + lyr * 128, att_dst + lyr * 128, as_, ad_);
    hipLaunchKernelGGL(k_agg, dim3((N_NODES + 7) / 8), dim3(256), 0, stream,
                       A16, et16 + (size_t)lyr * ETOT * 4, as_, ad_, offs, srcp,
                       last ? bias_last : (bias_cat + lyr * 128),
                       B16, (float*)d_out, last);
    hin = B16;
  }
}